// Round 1
// baseline (72.089 us; speedup 1.0000x reference)
//
#include <hip/hip_runtime.h>
#include <math.h>

#define TY 8
#define TX 64
#define AH (TY + 7)   // 15  ang rows
#define AW (TX + 7)   // 71  ang cols
#define PH (TY + 4)   // 12  pooled rows
#define PW (TX + 4)   // 68  pooled cols
#define H 512
#define W 512
#define NB 8

// LDS layout (bytes):
//   [0, 32640)        s_angx  [AH][NB][PW]  (15*8*68*4)
//   [32640, 36900)    s_w0    [AH*AW]
//   [36900, 41160)    s_w1    [AH*AW]
//   [41160, 45420)    s_b0    [AH*AW]
//   [32640, 58752)    s_pool  [PH][NB][PW]  (aliases compact; valid after stage 3 barrier)
#define SMEM_BYTES 58752

__global__ __launch_bounds__(256, 2) void sift_kernel(const float* __restrict__ x,
                                                      float* __restrict__ out) {
    __shared__ __align__(16) char smem[SMEM_BYTES];
    float* s_angx = (float*)smem;              // [AH][NB][PW]
    float* s_w0   = (float*)(smem + 32640);
    float* s_w1   = (float*)(smem + 36900);
    int*   s_b0   = (int*)(smem + 41160);
    float* s_pool = (float*)(smem + 32640);    // [PH][NB][PW], aliases compact ang

    const int tid = threadIdx.x;
    const int x0 = blockIdx.x * TX;
    const int y0 = blockIdx.y * TY;
    const int b  = blockIdx.z;
    const float* __restrict__ xb = x + (size_t)b * H * W;

    const float K1[4] = {0.25f, 0.75f, 0.75f, 0.25f};

    // ---- Stage 1: compact soft-binned gradient (b0, w0, w1) per ang pixel ----
    // ang pixel (ay,ax) <-> global (y0-3+ay, x0-3+ax); zero outside image
    // (implements the zero-padding of the pooling conv).
    for (int i = tid; i < AH * AW; i += 256) {
        int ay = i / AW, ax = i - ay * AW;
        int gy = y0 - 3 + ay, gx = x0 - 3 + ax;
        float w0 = 0.f, w1 = 0.f;
        int bin = 0;
        if (gy >= 0 && gy < H && gx >= 0 && gx < W) {
            int gxm = gx - 1 < 0 ? 0 : gx - 1;
            int gxp = gx + 1 > W - 1 ? W - 1 : gx + 1;
            int gym = gy - 1 < 0 ? 0 : gy - 1;
            int gyp = gy + 1 > H - 1 ? H - 1 : gy + 1;
            float xm = xb[gy * W + gxm];
            float xp = xb[gy * W + gxp];
            float ym = xb[gym * W + gx];
            float yp = xb[gyp * W + gx];
            float gxv = 0.5f * (xp - xm);
            float gyv = 0.5f * (yp - ym);
            float mag = sqrtf(gxv * gxv + gyv * gyv + 1e-10f);
            float ori = atan2f(gyv, gxv + 1e-10f) + 6.283185307179586f;
            float obig = ori * 1.2732395447351628f;  // * 8 / (2*pi)
            float bof = floorf(obig);
            float wo1 = obig - bof;
            bin = ((int)bof) & 7;
            w0 = (1.f - wo1) * mag;
            w1 = wo1 * mag;
        }
        s_w0[i] = w0;
        s_w1[i] = w1;
        s_b0[i] = bin;
    }
    __syncthreads();

    // ---- Stage 2: horizontal 1D conv + angular scatter -> s_angx[ay][d][pxl] ----
    for (int i = tid; i < AH * PW; i += 256) {
        int ay = i / PW, pxl = i - ay * PW;
        float acc[NB] = {0.f, 0.f, 0.f, 0.f, 0.f, 0.f, 0.f, 0.f};
        #pragma unroll
        for (int v = 0; v < 4; ++v) {
            int a = ay * AW + pxl + v;
            float c0 = K1[v] * s_w0[a];
            float c1 = K1[v] * s_w1[a];
            int bb = s_b0[a];
            int b1 = (bb + 1) & 7;
            #pragma unroll
            for (int d = 0; d < NB; ++d) {
                acc[d] += (bb == d ? c0 : 0.f) + (b1 == d ? c1 : 0.f);
            }
        }
        #pragma unroll
        for (int d = 0; d < NB; ++d)
            s_angx[(ay * NB + d) * PW + pxl] = acc[d];
    }
    __syncthreads();

    // ---- Stage 3: vertical 1D conv -> s_pool[pyl][d][pxl] (aliases compact) ----
    for (int i = tid; i < PH * PW; i += 256) {
        int pyl = i / PW, pxl = i - pyl * PW;
        #pragma unroll
        for (int d = 0; d < NB; ++d) {
            float s = 0.f;
            #pragma unroll
            for (int u = 0; u < 4; ++u)
                s += K1[u] * s_angx[((pyl + u) * NB + d) * PW + pxl];
            s_pool[(pyl * NB + d) * PW + pxl] = s;
        }
    }
    __syncthreads();

    // ---- Final: gather 128 channels, fused normalize chain, coalesced store ----
    // out[c=(d,ky,kx)] = pooled[d, y-1+ky, x-1+kx] (zero outside [0,512]^2 pooled grid)
    // norm chain collapses: u = min(v/max(||v||,1e-12), 0.2); out = sqrt(u/sum(u) + 1e-10)
    const int tx  = tid & 63;
    const int ty0 = tid >> 6;
    #pragma unroll
    for (int pp = 0; pp < 2; ++pp) {
        const int ty = ty0 + pp * 4;
        const int yy = y0 + ty;
        const int xx = x0 + tx;
        float mY[4], mX[4];
        #pragma unroll
        for (int k = 0; k < 4; ++k) {
            int py = yy - 1 + k;
            int px = xx - 1 + k;
            mY[k] = (py >= 0 && py <= H) ? 1.f : 0.f;   // pooled rows 0..512 valid
            mX[k] = (px >= 0 && px <= W) ? 1.f : 0.f;
        }
        float v[128];
        float ss[4] = {0.f, 0.f, 0.f, 0.f};
        #pragma unroll
        for (int d = 0; d < NB; ++d) {
            #pragma unroll
            for (int ky = 0; ky < 4; ++ky) {
                #pragma unroll
                for (int kx = 0; kx < 4; ++kx) {
                    const int c = d * 16 + ky * 4 + kx;
                    float t = s_pool[((ty + ky) * NB + d) * PW + (tx + kx)] * (mY[ky] * mX[kx]);
                    v[c] = t;
                    ss[c & 3] = fmaf(t, t, ss[c & 3]);
                }
            }
        }
        float ssq = (ss[0] + ss[1]) + (ss[2] + ss[3]);
        float inv = 1.f / fmaxf(sqrtf(ssq), 1e-12f);
        float us[4] = {0.f, 0.f, 0.f, 0.f};
        #pragma unroll
        for (int c = 0; c < 128; ++c) {
            float u = fminf(v[c] * inv, 0.2f);
            v[c] = u;
            us[c & 3] += u;
        }
        float su = (us[0] + us[1]) + (us[2] + us[3]);
        float rs = 1.f / fmaxf(su, 1e-12f);
        float* __restrict__ op = out + ((size_t)b * 128) * (H * (size_t)W) + (size_t)yy * W + xx;
        #pragma unroll
        for (int c = 0; c < 128; ++c) {
            op[(size_t)c * (H * (size_t)W)] = sqrtf(v[c] * rs + 1e-10f);
        }
    }
}

extern "C" void kernel_launch(void* const* d_in, const int* in_sizes, int n_in,
                              void* d_out, int out_size, void* d_ws, size_t ws_size,
                              hipStream_t stream) {
    const float* x = (const float*)d_in[0];
    float* out = (float*)d_out;
    const int B = in_sizes[0] / (H * W);   // = 2
    dim3 grid(W / TX, H / TY, B);
    dim3 block(256);
    hipLaunchKernelGGL(sift_kernel, grid, block, 0, stream, x, out);
    (void)n_in; (void)out_size; (void)d_ws; (void)ws_size;
}

// Round 2
// 58.783 us; speedup vs baseline: 1.2263x; 1.2263x over previous
//
#include <hip/hip_runtime.h>
#include <hip/hip_fp16.h>
#include <math.h>

#define TY 4
#define TX 64
#define AH (TY + 6)   // 10 ang rows   (global y0-3 .. y0+TY+2)
#define AW (TX + 6)   // 70 ang cols
#define PH (TY + 3)   // 7  pooled rows (global y0-1 .. y0+TY+1)
#define PW (TX + 3)   // 67 pooled cols
#define H 512
#define W 512

// LDS layout (bytes):
//   [0, 21440)        s_angx  f32 [AH][2][PW][4]   (10*2*67*16)
//   [21440, 32640)    s_ang   f16x8 [AH][AW]       (700 * 16B)  -- dead after stage 2
//   [21440, 36448)    s_pool  f32 [PH][2][PW][4]   (14*67*16)   -- aliases s_ang
#define ANGX_OFF 0
#define ANG_OFF  21440
#define POOL_OFF 21440
#define SMEM_BYTES 36448

__device__ __forceinline__ unsigned short f2h(float f) {
    return __half_as_ushort(__float2half(f));
}
__device__ __forceinline__ float h2f_lo(unsigned int u) {
    return __half2float(__ushort_as_half((unsigned short)(u & 0xffffu)));
}
__device__ __forceinline__ float h2f_hi(unsigned int u) {
    return __half2float(__ushort_as_half((unsigned short)(u >> 16)));
}

__global__ __launch_bounds__(256, 4) void sift_kernel(const float* __restrict__ x,
                                                      float* __restrict__ out) {
    __shared__ __align__(16) char smem[SMEM_BYTES];
    float4* s_angx = (float4*)(smem + ANGX_OFF);   // [(ay*2+dh)*PW + pxl]
    uint4*  s_ang  = (uint4*)(smem + ANG_OFF);     // [ay*AW + ax], 8 ch f16
    float4* s_pool = (float4*)(smem + POOL_OFF);   // [(pyl*2+dh)*PW + pxl]

    const int tid = threadIdx.x;
    const int x0 = blockIdx.x * TX;
    const int y0 = blockIdx.y * TY;
    const int b  = blockIdx.z;
    const float* __restrict__ xb = x + (size_t)b * H * W;

    const float K1[4] = {0.25f, 0.75f, 0.75f, 0.25f};

    // ---- Stage 1: gradient + soft-bin, packed f16x8 scatter ----
    // ang local (ay,ax) <-> global (y0-3+ay, x0-3+ax); zero outside image.
    for (int i = tid; i < AH * AW; i += 256) {
        int ay = i / AW, ax = i - ay * AW;
        int gy = y0 - 3 + ay, gx = x0 - 3 + ax;
        float w0 = 0.f, w1 = 0.f;
        int bin = 0;
        if (gy >= 0 && gy < H && gx >= 0 && gx < W) {
            int gxm = gx - 1 < 0 ? 0 : gx - 1;
            int gxp = gx + 1 > W - 1 ? W - 1 : gx + 1;
            int gym = gy - 1 < 0 ? 0 : gy - 1;
            int gyp = gy + 1 > H - 1 ? H - 1 : gy + 1;
            float gxv = 0.5f * (xb[gy * W + gxp] - xb[gy * W + gxm]);
            float gyv = 0.5f * (xb[gyp * W + gx] - xb[gym * W + gx]);
            float mag = sqrtf(gxv * gxv + gyv * gyv + 1e-10f);
            float ori = atan2f(gyv, gxv + 1e-10f) + 6.283185307179586f;
            float obig = ori * 1.2732395447351628f;  // * 8 / (2*pi)
            float bof = floorf(obig);
            float wo1 = obig - bof;
            bin = ((int)bof) & 7;
            w0 = (1.f - wo1) * mag;
            w1 = wo1 * mag;
        }
        // channels: dword j holds ch 2j (lo) | ch 2j+1 (hi); ch bin += w0, ch bin+1 += w1
        unsigned short h0 = f2h(w0), h1 = f2h(w1);
        unsigned int pack01 = (unsigned int)h0 | ((unsigned int)h1 << 16);
        unsigned int ph0 = (unsigned int)h0 << 16;
        unsigned int pl1 = (unsigned int)h1;
        int j0 = bin >> 1;
        int j1 = ((bin + 1) & 7) >> 1;
        bool ev = (bin & 1) == 0;
        uint4 d;
        d.x = ev ? (j0 == 0 ? pack01 : 0u) : ((j0 == 0 ? ph0 : 0u) | (j1 == 0 ? pl1 : 0u));
        d.y = ev ? (j0 == 1 ? pack01 : 0u) : ((j0 == 1 ? ph0 : 0u) | (j1 == 1 ? pl1 : 0u));
        d.z = ev ? (j0 == 2 ? pack01 : 0u) : ((j0 == 2 ? ph0 : 0u) | (j1 == 2 ? pl1 : 0u));
        d.w = ev ? (j0 == 3 ? pack01 : 0u) : ((j0 == 3 ? ph0 : 0u) | (j1 == 3 ? pl1 : 0u));
        s_ang[i] = d;
    }
    __syncthreads();

    // ---- Stage 2: horizontal 1D conv (f16 in, f32 out) ----
    for (int i = tid; i < AH * PW; i += 256) {
        int ay = i / PW, pxl = i - ay * PW;
        float acc[8] = {0.f, 0.f, 0.f, 0.f, 0.f, 0.f, 0.f, 0.f};
        int base = ay * AW + pxl;
        #pragma unroll
        for (int v = 0; v < 4; ++v) {
            uint4 q = s_ang[base + v];
            float k = K1[v];
            acc[0] = fmaf(k, h2f_lo(q.x), acc[0]);
            acc[1] = fmaf(k, h2f_hi(q.x), acc[1]);
            acc[2] = fmaf(k, h2f_lo(q.y), acc[2]);
            acc[3] = fmaf(k, h2f_hi(q.y), acc[3]);
            acc[4] = fmaf(k, h2f_lo(q.z), acc[4]);
            acc[5] = fmaf(k, h2f_hi(q.z), acc[5]);
            acc[6] = fmaf(k, h2f_lo(q.w), acc[6]);
            acc[7] = fmaf(k, h2f_hi(q.w), acc[7]);
        }
        s_angx[(ay * 2 + 0) * PW + pxl] = make_float4(acc[0], acc[1], acc[2], acc[3]);
        s_angx[(ay * 2 + 1) * PW + pxl] = make_float4(acc[4], acc[5], acc[6], acc[7]);
    }
    __syncthreads();

    // ---- Stage 3: vertical 1D conv -> s_pool (aliases s_ang) + boundary zero ----
    for (int i = tid; i < PH * PW * 2; i += 256) {
        int row = i / PW, pxl = i - row * PW;   // row = pyl*2 + dh
        int pyl = row >> 1, dh = row & 1;
        float4 s = make_float4(0.f, 0.f, 0.f, 0.f);
        #pragma unroll
        for (int u = 0; u < 4; ++u) {
            float4 a = s_angx[((pyl + u) * 2 + dh) * PW + pxl];
            float k = K1[u];
            s.x = fmaf(k, a.x, s.x);
            s.y = fmaf(k, a.y, s.y);
            s.z = fmaf(k, a.z, s.z);
            s.w = fmaf(k, a.w, s.w);
        }
        // pooled valid global coords: [0,512] inclusive both dims
        bool valid = ((unsigned)(y0 - 1 + pyl) <= 512u) && ((unsigned)(x0 - 1 + pxl) <= 512u);
        if (!valid) s = make_float4(0.f, 0.f, 0.f, 0.f);
        s_pool[row * PW + pxl] = s;
    }
    __syncthreads();

    // ---- Epilogue: 2 threads per pixel (channel halves), fused norm chain ----
    const int w  = tid >> 6;
    const int l  = tid & 63;
    const int dh = l >> 5;
    const int tx = 32 * (w & 1) + (l & 31);
    const int xx = x0 + tx;

    #pragma unroll
    for (int pp = 0; pp < 2; ++pp) {
        const int ty = 2 * pp + (w >> 1);
        const int yy = y0 + ty;
        float4 r[16];
        float ssq = 0.f;
        #pragma unroll
        for (int ky = 0; ky < 4; ++ky) {
            #pragma unroll
            for (int kx = 0; kx < 4; ++kx) {
                float4 t = s_pool[((ty + ky) * 2 + dh) * PW + (tx + kx)];
                r[ky * 4 + kx] = t;
                ssq = fmaf(t.x, t.x, ssq);
                ssq = fmaf(t.y, t.y, ssq);
                ssq = fmaf(t.z, t.z, ssq);
                ssq = fmaf(t.w, t.w, ssq);
            }
        }
        ssq += __shfl_xor(ssq, 32, 64);
        float inv = 1.f / fmaxf(sqrtf(ssq), 1e-12f);
        float su = 0.f;
        #pragma unroll
        for (int m = 0; m < 16; ++m) {
            float4 t = r[m];
            t.x = fminf(t.x * inv, 0.2f);
            t.y = fminf(t.y * inv, 0.2f);
            t.z = fminf(t.z * inv, 0.2f);
            t.w = fminf(t.w * inv, 0.2f);
            r[m] = t;
            su += (t.x + t.y) + (t.z + t.w);
        }
        su += __shfl_xor(su, 32, 64);
        float rs = 1.f / fmaxf(su, 1e-12f);
        // c = dh*64 + dd*16 + ky*4 + kx
        float* __restrict__ op = out + ((size_t)b * 128 + dh * 64) * (size_t)(H * W)
                                     + (size_t)yy * W + xx;
        #pragma unroll
        for (int dd = 0; dd < 4; ++dd) {
            #pragma unroll
            for (int m = 0; m < 16; ++m) {
                float4 t = r[m];
                float comp = (dd == 0) ? t.x : (dd == 1) ? t.y : (dd == 2) ? t.z : t.w;
                float val = sqrtf(fmaf(comp, rs, 1e-10f));
                __builtin_nontemporal_store(val, op + (size_t)(dd * 16 + m) * (H * W));
            }
        }
    }
}

extern "C" void kernel_launch(void* const* d_in, const int* in_sizes, int n_in,
                              void* d_out, int out_size, void* d_ws, size_t ws_size,
                              hipStream_t stream) {
    const float* x = (const float*)d_in[0];
    float* out = (float*)d_out;
    const int B = in_sizes[0] / (H * W);   // = 2
    dim3 grid(W / TX, H / TY, B);
    dim3 block(256);
    hipLaunchKernelGGL(sift_kernel, grid, block, 0, stream, x, out);
    (void)n_in; (void)out_size; (void)d_ws; (void)ws_size;
}